// Round 2
// baseline (115.953 us; speedup 1.0000x reference)
//
#include <hip/hip_runtime.h>
#include <hip/hip_bf16.h>
#include <hip/hip_cooperative_groups.h>
#include <math.h>

// Problem constants
#define NB 4
#define NC 4
#define NH 4
#define NN 1024
#define NF 64
#define NCOMBO 64
#define LEAK 0.2f

typedef __attribute__((ext_vector_type(8)))  short  short8;
typedef __attribute__((ext_vector_type(16))) float  float16;

// packed RNE f32x2 -> bf16x2 via v_cvt_pk_bf16_f32 (.x -> low 16, .y -> high 16)
static __device__ __forceinline__ unsigned pk_bf16(float a, float b) {
    union { __hip_bfloat162 h; unsigned u; } cv;
    cv.h = __float22bfloat162_rn(make_float2(a, b));
    return cv.u;
}

// tanh via hardware exp+rcp: 1 - 2/(1+e^{2x}); err ~1e-6, saturates correctly
static __device__ __forceinline__ float fast_tanh(float x) {
    const float e = __expf(2.f * x);
    return 1.f - 2.f * __builtin_amdgcn_rcpf(1.f + e);
}

// zero p unless bit k of bb is set (sign-extend bitfield -> and)
static __device__ __forceinline__ float mask_by_bit(float p, unsigned bb, int k) {
    const int m = -(int)((bb >> k) & 1u);
    union { float f; int i; } u;
    u.f = p; u.i &= m;
    return u.f;
}

// split 8 fp32 -> hi/lo bf16 short8 pair (x = hi + lo, both RNE bf16)
static __device__ __forceinline__ void split8(const float4 a, const float4 b,
                                              short8* hi, short8* lo) {
    union { short8 v; unsigned u[4]; } H, L;
    const float x[8] = {a.x,a.y,a.z,a.w,b.x,b.y,b.z,b.w};
    float lov[8];
    #pragma unroll
    for (int p = 0; p < 4; ++p) {
        const unsigned pk = pk_bf16(x[2*p], x[2*p+1]);
        H.u[p] = pk;
        union { unsigned u; float f; } f0, f1;
        f0.u = pk << 16; f1.u = pk & 0xffff0000u;
        lov[2*p]   = x[2*p]   - f0.f;
        lov[2*p+1] = x[2*p+1] - f1.f;
    }
    #pragma unroll
    for (int p = 0; p < 4; ++p) L.u[p] = pk_bf16(lov[2*p], lov[2*p+1]);
    *hi = H.v; *lo = L.v;
}

// ---------------------------------------------------------------------------
// Phase A body (identical math to the verified gA_produce).
// smem layout: [0,16384) w_s fp32 [64][64] -> overlay whi/wlo
//              [16384,16640) as_lds | [16640,16896) ad_lds
//              [16896,17408) scS[64][2] | [17408,17920) scD[64][2]
// ---------------------------------------------------------------------------
static __device__ __forceinline__ void phaseA(
    char* smem, const int idx, const int t,
    const float* __restrict__ h, const float* __restrict__ adj,
    const float* __restrict__ w, const float* __restrict__ a_src,
    const float* __restrict__ a_dst,
    unsigned short* __restrict__ hpt, float* __restrict__ asrc,
    float* __restrict__ edPt, float* __restrict__ edNt,
    unsigned long long* __restrict__ bits)
{
    float* w_s    = (float*)smem;
    unsigned short* whi = (unsigned short*)smem;          // 4096 bf16
    unsigned short* wlo = (unsigned short*)(smem + 8192); // 4096 bf16
    float* as_lds = (float*)(smem + 16384);
    float* ad_lds = (float*)(smem + 16640);
    float* scS    = (float*)(smem + 16896);
    float* scD    = (float*)(smem + 17408);

    const int g    = (idx & 7)*8 + ((idx >> 3) & 7);   // 0..63
    const int tile = idx >> 6;                          // 0..15
    const int b = g >> 4, c = (g >> 2) & 3, hh = g & 3;
    const int lane = t & 63, l31 = lane & 31, half = lane >> 5;
    const int wv = t >> 6, rg = wv >> 1, oh = wv & 1;

    // ---- stage w fp32 + score vectors ----
    const float4* wsrc = (const float4*)(w + ((size_t)(c*NH + hh))*NF*NF);
    #pragma unroll
    for (int i = 0; i < 4; ++i)
        ((float4*)w_s)[t + i*256] = wsrc[t + i*256];
    if (t < NF) {
        as_lds[t] = a_src[(c*NH + hh)*NF + t];
        ad_lds[t] = a_dst[(c*NH + hh)*NF + t];
    }
    __syncthreads();

    // ---- read w values for B-frag packing into regs (before overlay) ----
    float wv0[8], wv1[8];
    {
        const int n = t & 31;
        #pragma unroll
        for (int j = 0; j < 8; ++j) {
            const int blk0 = t >> 5, blk1 = (t >> 5) + 8;
            const int k0 = (blk0 >> 2)*16 + (blk0 & 1)*8 + j;
            const int o0 = ((blk0 >> 1) & 1)*32 + n;
            const int k1 = (blk1 >> 2)*16 + (blk1 & 1)*8 + j;
            const int o1 = ((blk1 >> 1) & 1)*32 + n;
            wv0[j] = w_s[k0*64 + o0];
            wv1[j] = w_s[k1*64 + o1];
        }
    }
    // ---- A-fragments: rows tile*64 + rg*32 + l31, k = s*16 + half*8 + j ----
    short8 ahi[4], alo[4];
    {
        const float* hrow = h +
            (((size_t)(b*NC + c))*NN + tile*64 + rg*32 + l31)*NF;
        #pragma unroll
        for (int s = 0; s < 4; ++s) {
            const float4 v0 = *(const float4*)&hrow[s*16 + half*8];
            const float4 v1 = *(const float4*)&hrow[s*16 + half*8 + 4];
            split8(v0, v1, &ahi[s], &alo[s]);
        }
    }
    __syncthreads();   // w_s reads done -> overlay frags

    // ---- write w B-frags (hi/lo) ----
    {
        union { short8 v; unsigned u[4]; } H; short8 L;
        float4 a0 = make_float4(wv0[0],wv0[1],wv0[2],wv0[3]);
        float4 a1 = make_float4(wv0[4],wv0[5],wv0[6],wv0[7]);
        split8(a0, a1, &H.v, &L);
        *(short8*)&whi[((t >> 5)*32 + (t & 31))*8] = H.v;
        *(short8*)&wlo[((t >> 5)*32 + (t & 31))*8] = L;
        a0 = make_float4(wv1[0],wv1[1],wv1[2],wv1[3]);
        a1 = make_float4(wv1[4],wv1[5],wv1[6],wv1[7]);
        split8(a0, a1, &H.v, &L);
        *(short8*)&whi[(((t >> 5) + 8)*32 + (t & 31))*8] = H.v;
        *(short8*)&wlo[(((t >> 5) + 8)*32 + (t & 31))*8] = L;
    }
    __syncthreads();

    // ---- MFMA: acc(32 rows x 32 o) = sum_s A[s] * B[s][oh] ----
    float16 acc;
    #pragma unroll
    for (int i = 0; i < 16; ++i) acc[i] = 0.f;
    #pragma unroll
    for (int s = 0; s < 4; ++s) {
        const short8 bhi = *(const short8*)&whi[(((s*2 + oh)*2 + half)*32 + l31)*8];
        const short8 blo = *(const short8*)&wlo[(((s*2 + oh)*2 + half)*32 + l31)*8];
        acc = __builtin_amdgcn_mfma_f32_32x32x16_bf16(ahi[s], bhi, acc, 0, 0, 0);
        acc = __builtin_amdgcn_mfma_f32_32x32x16_bf16(alo[s], bhi, acc, 0, 0, 0);
        acc = __builtin_amdgcn_mfma_f32_32x32x16_bf16(ahi[s], blo, acc, 0, 0, 0);
    }

    // ---- scores: s[row] = sum_o tanh(hp)*a[o]; butterfly over 32 cols ----
    {
        const int col = oh*32 + l31;
        const float av = as_lds[col], dv = ad_lds[col];
        float sS[16], sD[16];
        #pragma unroll
        for (int reg = 0; reg < 16; ++reg) {
            const float tt = fast_tanh(acc[reg]);
            sS[reg] = tt * av;
            sD[reg] = tt * dv;
        }
        #pragma unroll
        for (int off = 1; off <= 16; off <<= 1) {
            #pragma unroll
            for (int reg = 0; reg < 16; ++reg) {
                sS[reg] += __shfl_xor(sS[reg], off);
                sD[reg] += __shfl_xor(sD[reg], off);
            }
        }
        if (l31 == 0) {
            #pragma unroll
            for (int reg = 0; reg < 16; ++reg) {
                const int row = rg*32 + (reg & 3) + 8*(reg >> 2) + 4*half;
                scS[row*2 + oh] = sS[reg];
                scD[row*2 + oh] = sD[reg];
            }
        }
    }

    // ---- hp -> hpt (bf16, frag order), coalesced 8B stores ----
    {
        unsigned short* dst = hpt + ((size_t)(g*16 + tile))*4096;
        #pragma unroll
        for (int q = 0; q < 4; ++q) {
            const int ks = rg*2 + (q >> 1), hf = q & 1;
            const int elem = (((ks*2 + oh)*2 + hf)*32 + l31)*8 + 4*half;
            uint2 pk;
            pk.x = pk_bf16(acc[q*4 + 0], acc[q*4 + 1]);
            pk.y = pk_bf16(acc[q*4 + 2], acc[q*4 + 3]);
            *(uint2*)&dst[elem] = pk;
        }
    }
    __syncthreads();
    if (t < 64) {
        const float s = scS[t*2] + scS[t*2 + 1];
        const float d = scD[t*2] + scD[t*2 + 1];
        asrc[(size_t)g*NN + tile*64 + t] = s;
        edPt[(size_t)g*NN + tile*64 + t] = __expf(d);
        edNt[(size_t)g*NN + tile*64 + t] = __expf(LEAK*d);
    }

    // ---- phase B: adjacency bitmask (this block's 4096-element chunk) ----
    {
        const int base = idx*4096;       // 1024 blocks x 4096 = 4M elements
        #pragma unroll
        for (int q = 0; q < 16; ++q) {
            const int e  = base + q*256 + t;
            const int j  = e & (NN-1);
            const int i  = (e >> 10) & (NN-1);
            const int bb = e >> 20;
            const bool pred = (adj[e] != 0.f) || (j == i);
            const unsigned long long m = __ballot(pred);
            if ((t & 63) == 0) bits[((size_t)bb*NN + i)*16 + (j >> 6)] = m;
        }
    }
}

// ---------------------------------------------------------------------------
// Phase C body (identical math to the verified R1 gC_attn).
// smem layout during loop: [0,4096) edP | [4096,8192) edN
//                          [8192,16896) bits u64[64][17]
// after loop: comb overlays [0,17408); psum2 at [17408,17920)
// ---------------------------------------------------------------------------
static __device__ __forceinline__ void phaseC(
    char* smem, const int idx, const int t,
    const unsigned short* __restrict__ hpt, const float* __restrict__ asrc,
    const float* __restrict__ edPt, const float* __restrict__ edNt,
    const unsigned long long* __restrict__ bits, float* __restrict__ out)
{
    float* edP_lds = (float*)smem;
    float* edN_lds = (float*)(smem + 4096);
    unsigned long long* bits_lds = (unsigned long long*)(smem + 8192);
    float* comb  = (float*)smem;
    float* psum2 = (float*)(smem + 17408);

    const int g   = (idx & 7)*8 + ((idx >> 3) & 7);
    const int it  = idx >> 6;
    const int b   = g >> 4;
    const int i0  = it*64;
    const int wv = t >> 6, lane = t & 63;
    const int l31 = lane & 31, half = lane >> 5;
    const int rg = wv >> 1, jh = wv & 1;
    const int myrow = rg*32 + l31;

    // ---- stage fp32 exp tables + padded bitmask rows (one barrier total) ----
    #pragma unroll
    for (int q = 0; q < 4; ++q) {
        const int j = q*256 + t;
        edP_lds[j] = edPt[(size_t)g*NN + j];
        edN_lds[j] = edNt[(size_t)g*NN + j];
    }
    {
        const unsigned long long* bsrc = bits + ((size_t)b*NN + i0)*16;
        #pragma unroll
        for (int q = 0; q < 4; ++q) {
            const int e = q*256 + t;
            bits_lds[(e >> 4)*17 + (e & 15)] = bsrc[e];
        }
    }
    const float sv    = asrc[(size_t)g*NN + i0 + myrow];
    const float ratio = __expf((LEAK - 1.f)*sv);
    __syncthreads();

    union { short8 v; unsigned short u[8]; } ONES;
    #pragma unroll
    for (int i = 0; i < 8; ++i) ONES.u[i] = 0x3F80;

    float16 acc0, acc1, acc2;
    #pragma unroll
    for (int i = 0; i < 16; ++i) { acc0[i] = 0.f; acc1[i] = 0.f; acc2[i] = 0.f; }

    const unsigned short* hb = hpt + (size_t)g*16*4096;

    // prefetch B-frags for step m=0 (jt=0, kk=0)
    short8 b0, b1;
    {
        const int ks = jh*2;
        b0 = *(const short8*)&hb[(((ks*2 + 0)*2 + half)*32 + l31)*8];
        b1 = *(const short8*)&hb[(((ks*2 + 1)*2 + half)*32 + l31)*8];
    }

    #pragma unroll
    for (int m = 0; m < 32; ++m) {
        const int jt = m >> 1;
        const int ks = jh*2 + (m & 1);
        const int jo = ks*16 + half*8;

        // issue next step's frag loads (hidden under this step's VALU+MFMA)
        short8 nb0, nb1;
        if (m < 31) {
            const int jt1 = (m + 1) >> 1;
            const int ks1 = jh*2 + ((m + 1) & 1);
            const size_t base1 = (size_t)jt1*4096;
            nb0 = *(const short8*)&hb[base1 + (((ks1*2 + 0)*2 + half)*32 + l31)*8];
            nb1 = *(const short8*)&hb[base1 + (((ks1*2 + 1)*2 + half)*32 + l31)*8];
        }

        const unsigned long long wb = bits_lds[myrow*17 + jt];
        const unsigned bb = (unsigned)(wb >> jo) & 0xffu;

        // broadcast ds_read_b128 x4 (addresses uniform per half-wave)
        const float4 P0 = *(const float4*)&edP_lds[jt*64 + jo];
        const float4 P1 = *(const float4*)&edP_lds[jt*64 + jo + 4];
        const float4 Q0 = *(const float4*)&edN_lds[jt*64 + jo];
        const float4 Q1 = *(const float4*)&edN_lds[jt*64 + jo + 4];
        const float Pp[8] = {P0.x,P0.y,P0.z,P0.w,P1.x,P1.y,P1.z,P1.w};
        const float Nv[8] = {Q0.x,Q0.y,Q0.z,Q0.w,Q1.x,Q1.y,Q1.z,Q1.w};

        float pv[8];
        #pragma unroll
        for (int e2 = 0; e2 < 8; ++e2)
            pv[e2] = mask_by_bit(fmaxf(Pp[e2], ratio*Nv[e2]), bb, e2);

        union { short8 v; unsigned u[4]; } af;
        af.u[0] = pk_bf16(pv[0], pv[1]);
        af.u[1] = pk_bf16(pv[2], pv[3]);
        af.u[2] = pk_bf16(pv[4], pv[5]);
        af.u[3] = pk_bf16(pv[6], pv[7]);

        acc2 = __builtin_amdgcn_mfma_f32_32x32x16_bf16(af.v, ONES.v, acc2, 0, 0, 0);
        acc0 = __builtin_amdgcn_mfma_f32_32x32x16_bf16(af.v, b0,     acc0, 0, 0, 0);
        acc1 = __builtin_amdgcn_mfma_f32_32x32x16_bf16(af.v, b1,     acc1, 0, 0, 0);

        if (m < 31) { b0 = nb0; b1 = nb1; }
    }

    __syncthreads();   // tables/bits dead; comb overlays smem from here

    if (l31 == 0) {
        #pragma unroll
        for (int reg = 0; reg < 16; ++reg) {
            const int r = (reg & 3) + 8*(reg >> 2) + 4*half;
            psum2[jh*64 + rg*32 + r] = acc2[reg];
        }
    }
    if (jh == 1) {
        float* cb = comb + (rg*64 + lane)*34;
        #pragma unroll
        for (int i = 0; i < 8; ++i) {
            float2 v0; v0.x = acc0[2*i]; v0.y = acc0[2*i+1];
            float2 v1; v1.x = acc1[2*i]; v1.y = acc1[2*i+1];
            *(float2*)&cb[2*i]      = v0;
            *(float2*)&cb[16 + 2*i] = v1;
        }
    }
    __syncthreads();
    if (jh == 0) {
        const float* cb = comb + (rg*64 + lane)*34;
        #pragma unroll
        for (int i = 0; i < 8; ++i) {
            const float2 v0 = *(const float2*)&cb[2*i];
            const float2 v1 = *(const float2*)&cb[16 + 2*i];
            acc0[2*i] += v0.x; acc0[2*i+1] += v0.y;
            acc1[2*i] += v1.x; acc1[2*i+1] += v1.y;
        }
        #pragma unroll
        for (int reg = 0; reg < 16; ++reg) {
            const int r = (reg & 3) + 8*(reg >> 2) + 4*half;
            const int row = rg*32 + r;
            const float inv = __builtin_amdgcn_rcpf(psum2[row] + psum2[64 + row]);
            const size_t base = ((size_t)g*NN + i0 + row)*NF;
            out[base + l31]      = acc0[reg] * inv;
            out[base + l31 + 32] = acc1[reg] * inv;
        }
    }
}

// ---------------------------------------------------------------------------
// Fused cooperative kernel: phase A -> device fence -> grid sync -> phase C.
// 1024 blocks x 256 threads; __launch_bounds__(256,4) guarantees 4 blocks/CU
// (VGPR<=128, LDS 17.9KB) so all 1024 blocks are co-resident for grid.sync.
// XCD swizzle (idx%8 == g>>3) identical across phases -> hpt stays in the
// producing XCD's L2 across the sync.
// ---------------------------------------------------------------------------
__global__ __launch_bounds__(256, 4) void fused_all(
    const float* __restrict__ h, const float* __restrict__ adj,
    const float* __restrict__ w, const float* __restrict__ a_src,
    const float* __restrict__ a_dst,
    unsigned short* __restrict__ hpt, float* __restrict__ asrc,
    float* __restrict__ edPt, float* __restrict__ edNt,
    unsigned long long* __restrict__ bits, float* __restrict__ out)
{
    __shared__ __align__(16) char smem[17920];
    const int idx = blockIdx.x;
    const int t   = threadIdx.x;

    phaseA(smem, idx, t, h, adj, w, a_src, a_dst, hpt, asrc, edPt, edNt, bits);

    __threadfence();                       // device-scope release (bits cross XCDs)
    cooperative_groups::this_grid().sync();

    phaseC(smem, idx, t, hpt, asrc, edPt, edNt, bits, out);
}

// ---------------------------------------------------------------------------
// Fallback pair (verified at 115.5us): identical phase bodies, two launches.
// ---------------------------------------------------------------------------
__global__ __launch_bounds__(256) void gA_produce(
    const float* __restrict__ h, const float* __restrict__ adj,
    const float* __restrict__ w, const float* __restrict__ a_src,
    const float* __restrict__ a_dst,
    unsigned short* __restrict__ hpt, float* __restrict__ asrc,
    float* __restrict__ edPt, float* __restrict__ edNt,
    unsigned long long* __restrict__ bits)
{
    __shared__ __align__(16) char smem[17920];
    phaseA(smem, blockIdx.x, threadIdx.x, h, adj, w, a_src, a_dst,
           hpt, asrc, edPt, edNt, bits);
}

__global__ __launch_bounds__(256, 4) void gC_attn(
    const unsigned short* __restrict__ hpt, const float* __restrict__ asrc,
    const float* __restrict__ edPt, const float* __restrict__ edNt,
    const unsigned long long* __restrict__ bits, float* __restrict__ out)
{
    __shared__ __align__(16) char smem[17920];
    phaseC(smem, blockIdx.x, threadIdx.x, hpt, asrc, edPt, edNt, bits, out);
}

// ---------------------------------------------------------------------------
extern "C" void kernel_launch(void* const* d_in, const int* in_sizes, int n_in,
                              void* d_out, int out_size, void* d_ws, size_t ws_size,
                              hipStream_t stream)
{
    const float* h     = (const float*)d_in[0];
    const float* adj   = (const float*)d_in[1];
    const float* w     = (const float*)d_in[2];
    const float* a_src = (const float*)d_in[3];
    const float* a_dst = (const float*)d_in[4];
    float* out = (float*)d_out;

    char* ws = (char*)d_ws;
    // ws: hpt bf16 [64][16][4096] frag-order (8,388,608) | asrc (262,144)
    //     | edP (262,144) | edN (262,144) | bits u64 [4][1024][16] (524,288)
    unsigned short* hpt = (unsigned short*)ws;
    float* asrc         = (float*)(ws + 8388608);
    float* edP          = (float*)(ws + 8388608 + 262144);
    float* edN          = (float*)(ws + 8388608 + 524288);
    unsigned long long* bits = (unsigned long long*)(ws + 8388608 + 786432);

    // Decide once: cooperative fusion requires 4 blocks/CU co-residency.
    static int coopOK = -1;
    if (coopOK < 0) {
        int attr = 0;
        if (hipDeviceGetAttribute(&attr, hipDeviceAttributeCooperativeLaunch, 0)
            != hipSuccess) attr = 0;
        int maxB = 0;
        if (hipOccupancyMaxActiveBlocksPerMultiprocessor(
                &maxB, (const void*)fused_all, 256, 0) != hipSuccess) maxB = 0;
        coopOK = (attr != 0 && maxB >= 4) ? 1 : 0;
    }

    bool done = false;
    if (coopOK == 1) {
        void* args[] = {(void*)&h, (void*)&adj, (void*)&w, (void*)&a_src,
                        (void*)&a_dst, (void*)&hpt, (void*)&asrc, (void*)&edP,
                        (void*)&edN, (void*)&bits, (void*)&out};
        if (hipLaunchCooperativeKernel((const void*)fused_all, dim3(1024),
                                       dim3(256), args, 0u, stream)
            == hipSuccess) {
            done = true;
        } else {
            coopOK = 0;   // runtime refused (e.g. capture) -> permanent fallback
        }
    }
    if (!done) {
        gA_produce<<<dim3(1024), dim3(256), 0, stream>>>(
            h, adj, w, a_src, a_dst, hpt, asrc, edP, edN, bits);
        gC_attn<<<dim3(1024), dim3(256), 0, stream>>>(
            hpt, asrc, edP, edN, bits, out);
    }
}

// Round 4
// 111.194 us; speedup vs baseline: 1.0428x; 1.0428x over previous
//
#include <hip/hip_runtime.h>
#include <hip/hip_bf16.h>
#include <math.h>

// Problem constants
#define NB 4
#define NC 4
#define NH 4
#define NN 1024
#define NF 64
#define NCOMBO 64
#define LEAK 0.2f

typedef __attribute__((ext_vector_type(8)))  short  short8;
typedef __attribute__((ext_vector_type(16))) float  float16;

// packed RNE f32x2 -> bf16x2 via v_cvt_pk_bf16_f32 (.x -> low 16, .y -> high 16)
static __device__ __forceinline__ unsigned pk_bf16(float a, float b) {
    union { __hip_bfloat162 h; unsigned u; } cv;
    cv.h = __float22bfloat162_rn(make_float2(a, b));
    return cv.u;
}

// tanh via hardware exp+rcp: 1 - 2/(1+e^{2x}); err ~1e-6, saturates correctly
static __device__ __forceinline__ float fast_tanh(float x) {
    const float e = __expf(2.f * x);
    return 1.f - 2.f * __builtin_amdgcn_rcpf(1.f + e);
}

// zero p unless bit k of bb is set (sign-extend bitfield -> and)
static __device__ __forceinline__ float mask_by_bit(float p, unsigned bb, int k) {
    const int m = -(int)((bb >> k) & 1u);
    union { float f; int i; } u;
    u.f = p; u.i &= m;
    return u.f;
}

// split 8 fp32 -> hi/lo bf16 short8 pair (x = hi + lo, both RNE bf16)
static __device__ __forceinline__ void split8(const float4 a, const float4 b,
                                              short8* hi, short8* lo) {
    union { short8 v; unsigned u[4]; } H, L;
    const float x[8] = {a.x,a.y,a.z,a.w,b.x,b.y,b.z,b.w};
    float lov[8];
    #pragma unroll
    for (int p = 0; p < 4; ++p) {
        const unsigned pk = pk_bf16(x[2*p], x[2*p+1]);
        H.u[p] = pk;
        union { unsigned u; float f; } f0, f1;
        f0.u = pk << 16; f1.u = pk & 0xffff0000u;
        lov[2*p]   = x[2*p]   - f0.f;
        lov[2*p+1] = x[2*p+1] - f1.f;
    }
    #pragma unroll
    for (int p = 0; p < 4; ++p) L.u[p] = pk_bf16(lov[2*p], lov[2*p+1]);
    *hi = H.v; *lo = L.v;
}

// ---------------------------------------------------------------------------
// gA (R4): producer. Same math as the verified kernel, restructured for
// latency: (1) adj loads hoisted to entry (HBM latency overlaps the GEMM;
// ballots at the end); (2) w gathered for frag-packing DIRECTLY from global
// (16 KB per combo, shared by 16 blocks -> L2-hot; 128B-contiguous per
// 32-lane group), removing the fp32 w_s LDS staging and 3 of 5 barriers.
// smem: [0,8192) whi | [8192,16384) wlo | [16384,16640) as | [16640,16896) ad
//       [16896,17408) scS[64][2] | [17408,17920) scD[64][2]
// ---------------------------------------------------------------------------
__global__ __launch_bounds__(256) void gA_produce(
    const float* __restrict__ h, const float* __restrict__ adj,
    const float* __restrict__ w, const float* __restrict__ a_src,
    const float* __restrict__ a_dst,
    unsigned short* __restrict__ hpt, float* __restrict__ asrc,
    float* __restrict__ edPt, float* __restrict__ edNt,
    unsigned long long* __restrict__ bits)
{
    __shared__ __align__(16) char smem[17920];
    unsigned short* whi = (unsigned short*)smem;          // 4096 bf16
    unsigned short* wlo = (unsigned short*)(smem + 8192); // 4096 bf16
    float* as_lds = (float*)(smem + 16384);
    float* ad_lds = (float*)(smem + 16640);
    float* scS    = (float*)(smem + 16896);
    float* scD    = (float*)(smem + 17408);

    const int idx  = blockIdx.x;
    const int t    = threadIdx.x;
    const int g    = (idx & 7)*8 + ((idx >> 3) & 7);   // 0..63
    const int tile = idx >> 6;                          // 0..15
    const int b = g >> 4, c = (g >> 2) & 3, hh = g & 3;
    const int lane = t & 63, l31 = lane & 31, half = lane >> 5;
    const int wv = t >> 6, rg = wv >> 1, oh = wv & 1;

    // ---- hoisted adjacency loads (consumed by ballots at the end) ----
    float av16[16];
    const int abase = idx*4096;          // 1024 blocks x 4096 = 4M elements
    #pragma unroll
    for (int q = 0; q < 16; ++q) av16[q] = adj[abase + q*256 + t];

    // ---- w gather straight from global (frag pattern; L2-hot) ----
    const float* wg = w + ((size_t)(c*NH + hh))*NF*NF;
    float wv0[8], wv1[8];
    {
        const int n = t & 31;
        #pragma unroll
        for (int j = 0; j < 8; ++j) {
            const int blk0 = t >> 5, blk1 = (t >> 5) + 8;
            const int k0 = (blk0 >> 2)*16 + (blk0 & 1)*8 + j;
            const int o0 = ((blk0 >> 1) & 1)*32 + n;
            const int k1 = (blk1 >> 2)*16 + (blk1 & 1)*8 + j;
            const int o1 = ((blk1 >> 1) & 1)*32 + n;
            wv0[j] = wg[k0*64 + o0];
            wv1[j] = wg[k1*64 + o1];
        }
    }
    if (t < NF) {
        as_lds[t] = a_src[(c*NH + hh)*NF + t];
        ad_lds[t] = a_dst[(c*NH + hh)*NF + t];
    }

    // ---- A-fragments: rows tile*64 + rg*32 + l31, k = s*16 + half*8 + j ----
    short8 ahi[4], alo[4];
    {
        const float* hrow = h +
            (((size_t)(b*NC + c))*NN + tile*64 + rg*32 + l31)*NF;
        #pragma unroll
        for (int s = 0; s < 4; ++s) {
            const float4 v0 = *(const float4*)&hrow[s*16 + half*8];
            const float4 v1 = *(const float4*)&hrow[s*16 + half*8 + 4];
            split8(v0, v1, &ahi[s], &alo[s]);
        }
    }

    // ---- write w B-frags (hi/lo) ----
    {
        union { short8 v; unsigned u[4]; } H; short8 L;
        float4 a0 = make_float4(wv0[0],wv0[1],wv0[2],wv0[3]);
        float4 a1 = make_float4(wv0[4],wv0[5],wv0[6],wv0[7]);
        split8(a0, a1, &H.v, &L);
        *(short8*)&whi[((t >> 5)*32 + (t & 31))*8] = H.v;
        *(short8*)&wlo[((t >> 5)*32 + (t & 31))*8] = L;
        a0 = make_float4(wv1[0],wv1[1],wv1[2],wv1[3]);
        a1 = make_float4(wv1[4],wv1[5],wv1[6],wv1[7]);
        split8(a0, a1, &H.v, &L);
        *(short8*)&whi[(((t >> 5) + 8)*32 + (t & 31))*8] = H.v;
        *(short8*)&wlo[(((t >> 5) + 8)*32 + (t & 31))*8] = L;
    }
    __syncthreads();    // frags + as/ad visible

    // ---- MFMA: acc(32 rows x 32 o) = sum_s A[s] * B[s][oh] ----
    float16 acc;
    #pragma unroll
    for (int i = 0; i < 16; ++i) acc[i] = 0.f;
    #pragma unroll
    for (int s = 0; s < 4; ++s) {
        const short8 bhi = *(const short8*)&whi[(((s*2 + oh)*2 + half)*32 + l31)*8];
        const short8 blo = *(const short8*)&wlo[(((s*2 + oh)*2 + half)*32 + l31)*8];
        acc = __builtin_amdgcn_mfma_f32_32x32x16_bf16(ahi[s], bhi, acc, 0, 0, 0);
        acc = __builtin_amdgcn_mfma_f32_32x32x16_bf16(alo[s], bhi, acc, 0, 0, 0);
        acc = __builtin_amdgcn_mfma_f32_32x32x16_bf16(ahi[s], blo, acc, 0, 0, 0);
    }

    // ---- scores: s[row] = sum_o tanh(hp)*a[o]; butterfly over 32 cols ----
    {
        const int col = oh*32 + l31;
        const float av = as_lds[col], dv = ad_lds[col];
        float sS[16], sD[16];
        #pragma unroll
        for (int reg = 0; reg < 16; ++reg) {
            const float tt = fast_tanh(acc[reg]);
            sS[reg] = tt * av;
            sD[reg] = tt * dv;
        }
        #pragma unroll
        for (int off = 1; off <= 16; off <<= 1) {
            #pragma unroll
            for (int reg = 0; reg < 16; ++reg) {
                sS[reg] += __shfl_xor(sS[reg], off);
                sD[reg] += __shfl_xor(sD[reg], off);
            }
        }
        if (l31 == 0) {
            #pragma unroll
            for (int reg = 0; reg < 16; ++reg) {
                const int row = rg*32 + (reg & 3) + 8*(reg >> 2) + 4*half;
                scS[row*2 + oh] = sS[reg];
                scD[row*2 + oh] = sD[reg];
            }
        }
    }

    // ---- hp -> hpt (bf16, frag order), coalesced 8B stores ----
    {
        unsigned short* dst = hpt + ((size_t)(g*16 + tile))*4096;
        #pragma unroll
        for (int q = 0; q < 4; ++q) {
            const int ks = rg*2 + (q >> 1), hf = q & 1;
            const int elem = (((ks*2 + oh)*2 + hf)*32 + l31)*8 + 4*half;
            uint2 pk;
            pk.x = pk_bf16(acc[q*4 + 0], acc[q*4 + 1]);
            pk.y = pk_bf16(acc[q*4 + 2], acc[q*4 + 3]);
            *(uint2*)&dst[elem] = pk;
        }
    }
    __syncthreads();    // scS/scD visible
    if (t < 64) {
        const float s = scS[t*2] + scS[t*2 + 1];
        const float d = scD[t*2] + scD[t*2 + 1];
        asrc[(size_t)g*NN + tile*64 + t] = s;
        edPt[(size_t)g*NN + tile*64 + t] = __expf(d);
        edNt[(size_t)g*NN + tile*64 + t] = __expf(LEAK*d);
    }

    // ---- adjacency bitmask from the hoisted values ----
    #pragma unroll
    for (int q = 0; q < 16; ++q) {
        const int e  = abase + q*256 + t;
        const int j  = e & (NN-1);
        const int i  = (e >> 10) & (NN-1);
        const int bb = e >> 20;
        const bool pred = (av16[q] != 0.f) || (j == i);
        const unsigned long long m = __ballot(pred);
        if ((t & 63) == 0) bits[((size_t)bb*NN + i)*16 + (j >> 6)] = m;
    }
}

// ---------------------------------------------------------------------------
// gC (R4): consumer, verified R1 structure + 3-slot register prefetch ring
// (B-frag loads issued 2 steps ahead; 1-deep was ~80cyc cover vs 200-400cyc
// L2 latency). All ring indices compile-time (full unroll) -> registers.
// smem during loop: [0,4096) edP | [4096,8192) edN | [8192,16896) bits[64][17]
// after loop: comb overlays [0,17408); psum2 at [17408,17920)
// ---------------------------------------------------------------------------
__global__ __launch_bounds__(256, 4) void gC_attn(
    const unsigned short* __restrict__ hpt, const float* __restrict__ asrc,
    const float* __restrict__ edPt, const float* __restrict__ edNt,
    const unsigned long long* __restrict__ bits, float* __restrict__ out)
{
    __shared__ __align__(16) char smem[17920];
    float* edP_lds = (float*)smem;
    float* edN_lds = (float*)(smem + 4096);
    unsigned long long* bits_lds = (unsigned long long*)(smem + 8192);
    float* comb  = (float*)smem;
    float* psum2 = (float*)(smem + 17408);

    const int idx = blockIdx.x;
    const int t   = threadIdx.x;
    const int g   = (idx & 7)*8 + ((idx >> 3) & 7);
    const int it  = idx >> 6;
    const int b   = g >> 4;
    const int i0  = it*64;
    const int wv = t >> 6, lane = t & 63;
    const int l31 = lane & 31, half = lane >> 5;
    const int rg = wv >> 1, jh = wv & 1;
    const int myrow = rg*32 + l31;

    // ---- stage fp32 exp tables + padded bitmask rows (one barrier total) ----
    #pragma unroll
    for (int q = 0; q < 4; ++q) {
        const int j = q*256 + t;
        edP_lds[j] = edPt[(size_t)g*NN + j];
        edN_lds[j] = edNt[(size_t)g*NN + j];
    }
    {
        const unsigned long long* bsrc = bits + ((size_t)b*NN + i0)*16;
        #pragma unroll
        for (int q = 0; q < 4; ++q) {
            const int e = q*256 + t;
            bits_lds[(e >> 4)*17 + (e & 15)] = bsrc[e];
        }
    }
    const float sv    = asrc[(size_t)g*NN + i0 + myrow];
    const float ratio = __expf((LEAK - 1.f)*sv);
    __syncthreads();

    union { short8 v; unsigned short u[8]; } ONES;
    #pragma unroll
    for (int i = 0; i < 8; ++i) ONES.u[i] = 0x3F80;

    float16 acc0, acc1, acc2;
    #pragma unroll
    for (int i = 0; i < 16; ++i) { acc0[i] = 0.f; acc1[i] = 0.f; acc2[i] = 0.f; }

    const unsigned short* hb = hpt + (size_t)g*16*4096;

    short8 B0[3], B1[3];
    #define LOADM(slot, mm) do { \
        const int jt_ = (mm) >> 1; \
        const int ks_ = jh*2 + ((mm) & 1); \
        const size_t base_ = (size_t)jt_*4096; \
        B0[slot] = *(const short8*)&hb[base_ + (((ks_*2 + 0)*2 + half)*32 + l31)*8]; \
        B1[slot] = *(const short8*)&hb[base_ + (((ks_*2 + 1)*2 + half)*32 + l31)*8]; \
    } while (0)

    LOADM(0, 0);
    LOADM(1, 1);

    #pragma unroll
    for (int m = 0; m < 32; ++m) {
        const int jt = m >> 1;
        const int ks = jh*2 + (m & 1);
        const int jo = ks*16 + half*8;

        // issue loads for m+2 (slot free: last consumed at m-1)
        if (m + 2 < 32) LOADM((m + 2) % 3, m + 2);

        const unsigned long long wb = bits_lds[myrow*17 + jt];
        const unsigned bb = (unsigned)(wb >> jo) & 0xffu;

        // broadcast ds_read_b128 x4 (addresses uniform per half-wave)
        const float4 P0 = *(const float4*)&edP_lds[jt*64 + jo];
        const float4 P1 = *(const float4*)&edP_lds[jt*64 + jo + 4];
        const float4 Q0 = *(const float4*)&edN_lds[jt*64 + jo];
        const float4 Q1 = *(const float4*)&edN_lds[jt*64 + jo + 4];
        const float Pp[8] = {P0.x,P0.y,P0.z,P0.w,P1.x,P1.y,P1.z,P1.w};
        const float Nv[8] = {Q0.x,Q0.y,Q0.z,Q0.w,Q1.x,Q1.y,Q1.z,Q1.w};

        float pv[8];
        #pragma unroll
        for (int e2 = 0; e2 < 8; ++e2)
            pv[e2] = mask_by_bit(fmaxf(Pp[e2], ratio*Nv[e2]), bb, e2);

        union { short8 v; unsigned u[4]; } af;
        af.u[0] = pk_bf16(pv[0], pv[1]);
        af.u[1] = pk_bf16(pv[2], pv[3]);
        af.u[2] = pk_bf16(pv[4], pv[5]);
        af.u[3] = pk_bf16(pv[6], pv[7]);

        acc2 = __builtin_amdgcn_mfma_f32_32x32x16_bf16(af.v, ONES.v, acc2, 0, 0, 0);
        acc0 = __builtin_amdgcn_mfma_f32_32x32x16_bf16(af.v, B0[m % 3], acc0, 0, 0, 0);
        acc1 = __builtin_amdgcn_mfma_f32_32x32x16_bf16(af.v, B1[m % 3], acc1, 0, 0, 0);
    }
    #undef LOADM

    __syncthreads();   // tables/bits dead; comb overlays smem from here

    if (l31 == 0) {
        #pragma unroll
        for (int reg = 0; reg < 16; ++reg) {
            const int r = (reg & 3) + 8*(reg >> 2) + 4*half;
            psum2[jh*64 + rg*32 + r] = acc2[reg];
        }
    }
    if (jh == 1) {
        float* cb = comb + (rg*64 + lane)*34;
        #pragma unroll
        for (int i = 0; i < 8; ++i) {
            float2 v0; v0.x = acc0[2*i]; v0.y = acc0[2*i+1];
            float2 v1; v1.x = acc1[2*i]; v1.y = acc1[2*i+1];
            *(float2*)&cb[2*i]      = v0;
            *(float2*)&cb[16 + 2*i] = v1;
        }
    }
    __syncthreads();
    if (jh == 0) {
        const float* cb = comb + (rg*64 + lane)*34;
        #pragma unroll
        for (int i = 0; i < 8; ++i) {
            const float2 v0 = *(const float2*)&cb[2*i];
            const float2 v1 = *(const float2*)&cb[16 + 2*i];
            acc0[2*i] += v0.x; acc0[2*i+1] += v0.y;
            acc1[2*i] += v1.x; acc1[2*i+1] += v1.y;
        }
        #pragma unroll
        for (int reg = 0; reg < 16; ++reg) {
            const int r = (reg & 3) + 8*(reg >> 2) + 4*half;
            const int row = rg*32 + r;
            const float inv = __builtin_amdgcn_rcpf(psum2[row] + psum2[64 + row]);
            const size_t base = ((size_t)g*NN + i0 + row)*NF;
            out[base + l31]      = acc0[reg] * inv;
            out[base + l31 + 32] = acc1[reg] * inv;
        }
    }
}

// ---------------------------------------------------------------------------
extern "C" void kernel_launch(void* const* d_in, const int* in_sizes, int n_in,
                              void* d_out, int out_size, void* d_ws, size_t ws_size,
                              hipStream_t stream)
{
    const float* h     = (const float*)d_in[0];
    const float* adj   = (const float*)d_in[1];
    const float* w     = (const float*)d_in[2];
    const float* a_src = (const float*)d_in[3];
    const float* a_dst = (const float*)d_in[4];
    float* out = (float*)d_out;

    char* ws = (char*)d_ws;
    // ws: hpt bf16 [64][16][4096] frag-order (8,388,608) | asrc (262,144)
    //     | edP (262,144) | edN (262,144) | bits u64 [4][1024][16] (524,288)
    unsigned short* hpt = (unsigned short*)ws;
    float* asrc         = (float*)(ws + 8388608);
    float* edP          = (float*)(ws + 8388608 + 262144);
    float* edN          = (float*)(ws + 8388608 + 524288);
    unsigned long long* bits = (unsigned long long*)(ws + 8388608 + 786432);

    gA_produce<<<dim3(1024), dim3(256), 0, stream>>>(
        h, adj, w, a_src, a_dst, hpt, asrc, edP, edN, bits);
    gC_attn<<<dim3(1024), dim3(256), 0, stream>>>(
        hpt, asrc, edP, edN, bits, out);
}

// Round 5
// 107.272 us; speedup vs baseline: 1.0809x; 1.0366x over previous
//
#include <hip/hip_runtime.h>
#include <hip/hip_bf16.h>
#include <math.h>

// Problem constants
#define NB 4
#define NC 4
#define NH 4
#define NN 1024
#define NF 64
#define NCOMBO 64
#define LEAK 0.2f

typedef __attribute__((ext_vector_type(8)))  short  short8;
typedef __attribute__((ext_vector_type(16))) float  float16;

// packed RNE f32x2 -> bf16x2 via v_cvt_pk_bf16_f32 (.x -> low 16, .y -> high 16)
static __device__ __forceinline__ unsigned pk_bf16(float a, float b) {
    union { __hip_bfloat162 h; unsigned u; } cv;
    cv.h = __float22bfloat162_rn(make_float2(a, b));
    return cv.u;
}

// tanh via hardware exp+rcp: 1 - 2/(1+e^{2x}); err ~1e-6, saturates correctly
static __device__ __forceinline__ float fast_tanh(float x) {
    const float e = __expf(2.f * x);
    return 1.f - 2.f * __builtin_amdgcn_rcpf(1.f + e);
}

// zero p unless bit k of bb is set (sign-extend bitfield -> and)
static __device__ __forceinline__ float mask_by_bit(float p, unsigned bb, int k) {
    const int m = -(int)((bb >> k) & 1u);
    union { float f; int i; } u;
    u.f = p; u.i &= m;
    return u.f;
}

// split 8 fp32 -> hi/lo bf16 short8 pair (x = hi + lo, both RNE bf16)
static __device__ __forceinline__ void split8(const float4 a, const float4 b,
                                              short8* hi, short8* lo) {
    union { short8 v; unsigned u[4]; } H, L;
    const float x[8] = {a.x,a.y,a.z,a.w,b.x,b.y,b.z,b.w};
    float lov[8];
    #pragma unroll
    for (int p = 0; p < 4; ++p) {
        const unsigned pk = pk_bf16(x[2*p], x[2*p+1]);
        H.u[p] = pk;
        union { unsigned u; float f; } f0, f1;
        f0.u = pk << 16; f1.u = pk & 0xffff0000u;
        lov[2*p]   = x[2*p]   - f0.f;
        lov[2*p+1] = x[2*p+1] - f1.f;
    }
    #pragma unroll
    for (int p = 0; p < 4; ++p) L.u[p] = pk_bf16(lov[2*p], lov[2*p+1]);
    *hi = H.v; *lo = L.v;
}

// ---------------------------------------------------------------------------
// gA (R5): R4 structure + fused sS/sD butterfly (lane-parity pairing: step-1
// reduces both arrays, cndmask packs sS->even lanes / sD->odd lanes, one
// shared 4-step tree finishes both; tree shape per value identical -> bit-
// exact, 13 ops/reg vs 20). Writers: l31==0 -> scS, l31==1 -> scD.
// smem: [0,8192) whi | [8192,16384) wlo | [16384,16640) as | [16640,16896) ad
//       [16896,17408) scS[64][2] | [17408,17920) scD[64][2]
// ---------------------------------------------------------------------------
__global__ __launch_bounds__(256, 4) void gA_produce(
    const float* __restrict__ h, const float* __restrict__ adj,
    const float* __restrict__ w, const float* __restrict__ a_src,
    const float* __restrict__ a_dst,
    unsigned short* __restrict__ hpt, float* __restrict__ asrc,
    float* __restrict__ edPt, float* __restrict__ edNt,
    unsigned long long* __restrict__ bits)
{
    __shared__ __align__(16) char smem[17920];
    unsigned short* whi = (unsigned short*)smem;          // 4096 bf16
    unsigned short* wlo = (unsigned short*)(smem + 8192); // 4096 bf16
    float* as_lds = (float*)(smem + 16384);
    float* ad_lds = (float*)(smem + 16640);
    float* scS    = (float*)(smem + 16896);
    float* scD    = (float*)(smem + 17408);

    const int idx  = blockIdx.x;
    const int t    = threadIdx.x;
    const int g    = (idx & 7)*8 + ((idx >> 3) & 7);   // 0..63
    const int tile = idx >> 6;                          // 0..15
    const int b = g >> 4, c = (g >> 2) & 3, hh = g & 3;
    const int lane = t & 63, l31 = lane & 31, half = lane >> 5;
    const int wv = t >> 6, rg = wv >> 1, oh = wv & 1;

    // ---- hoisted adjacency loads (consumed by ballots at the end) ----
    float av16[16];
    const int abase = idx*4096;          // 1024 blocks x 4096 = 4M elements
    #pragma unroll
    for (int q = 0; q < 16; ++q) av16[q] = adj[abase + q*256 + t];

    // ---- w gather straight from global (frag pattern; L2-hot) ----
    const float* wg = w + ((size_t)(c*NH + hh))*NF*NF;
    float wv0[8], wv1[8];
    {
        const int n = t & 31;
        #pragma unroll
        for (int j = 0; j < 8; ++j) {
            const int blk0 = t >> 5, blk1 = (t >> 5) + 8;
            const int k0 = (blk0 >> 2)*16 + (blk0 & 1)*8 + j;
            const int o0 = ((blk0 >> 1) & 1)*32 + n;
            const int k1 = (blk1 >> 2)*16 + (blk1 & 1)*8 + j;
            const int o1 = ((blk1 >> 1) & 1)*32 + n;
            wv0[j] = wg[k0*64 + o0];
            wv1[j] = wg[k1*64 + o1];
        }
    }
    if (t < NF) {
        as_lds[t] = a_src[(c*NH + hh)*NF + t];
        ad_lds[t] = a_dst[(c*NH + hh)*NF + t];
    }

    // ---- A-fragments: rows tile*64 + rg*32 + l31, k = s*16 + half*8 + j ----
    short8 ahi[4], alo[4];
    {
        const float* hrow = h +
            (((size_t)(b*NC + c))*NN + tile*64 + rg*32 + l31)*NF;
        #pragma unroll
        for (int s = 0; s < 4; ++s) {
            const float4 v0 = *(const float4*)&hrow[s*16 + half*8];
            const float4 v1 = *(const float4*)&hrow[s*16 + half*8 + 4];
            split8(v0, v1, &ahi[s], &alo[s]);
        }
    }

    // ---- write w B-frags (hi/lo) ----
    {
        union { short8 v; unsigned u[4]; } H; short8 L;
        float4 a0 = make_float4(wv0[0],wv0[1],wv0[2],wv0[3]);
        float4 a1 = make_float4(wv0[4],wv0[5],wv0[6],wv0[7]);
        split8(a0, a1, &H.v, &L);
        *(short8*)&whi[((t >> 5)*32 + (t & 31))*8] = H.v;
        *(short8*)&wlo[((t >> 5)*32 + (t & 31))*8] = L;
        a0 = make_float4(wv1[0],wv1[1],wv1[2],wv1[3]);
        a1 = make_float4(wv1[4],wv1[5],wv1[6],wv1[7]);
        split8(a0, a1, &H.v, &L);
        *(short8*)&whi[(((t >> 5) + 8)*32 + (t & 31))*8] = H.v;
        *(short8*)&wlo[(((t >> 5) + 8)*32 + (t & 31))*8] = L;
    }
    __syncthreads();    // frags + as/ad visible

    // ---- MFMA: acc(32 rows x 32 o) = sum_s A[s] * B[s][oh] ----
    float16 acc;
    #pragma unroll
    for (int i = 0; i < 16; ++i) acc[i] = 0.f;
    #pragma unroll
    for (int s = 0; s < 4; ++s) {
        const short8 bhi = *(const short8*)&whi[(((s*2 + oh)*2 + half)*32 + l31)*8];
        const short8 blo = *(const short8*)&wlo[(((s*2 + oh)*2 + half)*32 + l31)*8];
        acc = __builtin_amdgcn_mfma_f32_32x32x16_bf16(ahi[s], bhi, acc, 0, 0, 0);
        acc = __builtin_amdgcn_mfma_f32_32x32x16_bf16(alo[s], bhi, acc, 0, 0, 0);
        acc = __builtin_amdgcn_mfma_f32_32x32x16_bf16(ahi[s], blo, acc, 0, 0, 0);
    }

    // ---- scores: fused sS/sD pair-butterfly over 32 cols ----
    {
        const int col = oh*32 + l31;
        const float av = as_lds[col], dv = ad_lds[col];
        float red[16];
        #pragma unroll
        for (int reg = 0; reg < 16; ++reg) {
            const float tt = fast_tanh(acc[reg]);
            const float sS = tt * av;
            const float sD = tt * dv;
            // step 1 on both arrays (same tree step as before -> bit-exact)
            const float s1 = sS + __shfl_xor(sS, 1);
            const float s2 = sD + __shfl_xor(sD, 1);
            float mm = (l31 & 1) ? s2 : s1;   // even lanes: sS, odd: sD
            #pragma unroll
            for (int off = 2; off <= 16; off <<= 1)
                mm += __shfl_xor(mm, off);
            red[reg] = mm;                     // lane0: sum sS, lane1: sum sD
        }
        if (l31 < 2) {
            float* dst = (l31 == 0) ? scS : scD;
            #pragma unroll
            for (int reg = 0; reg < 16; ++reg) {
                const int row = rg*32 + (reg & 3) + 8*(reg >> 2) + 4*half;
                dst[row*2 + oh] = red[reg];
            }
        }
    }

    // ---- hp -> hpt (bf16, frag order), coalesced 8B stores ----
    {
        unsigned short* dst = hpt + ((size_t)(g*16 + tile))*4096;
        #pragma unroll
        for (int q = 0; q < 4; ++q) {
            const int ks = rg*2 + (q >> 1), hf = q & 1;
            const int elem = (((ks*2 + oh)*2 + hf)*32 + l31)*8 + 4*half;
            uint2 pk;
            pk.x = pk_bf16(acc[q*4 + 0], acc[q*4 + 1]);
            pk.y = pk_bf16(acc[q*4 + 2], acc[q*4 + 3]);
            *(uint2*)&dst[elem] = pk;
        }
    }
    __syncthreads();    // scS/scD visible
    if (t < 64) {
        const float s = scS[t*2] + scS[t*2 + 1];
        const float d = scD[t*2] + scD[t*2 + 1];
        asrc[(size_t)g*NN + tile*64 + t] = s;
        edPt[(size_t)g*NN + tile*64 + t] = __expf(d);
        edNt[(size_t)g*NN + tile*64 + t] = __expf(LEAK*d);
    }

    // ---- adjacency bitmask from the hoisted values ----
    #pragma unroll
    for (int q = 0; q < 16; ++q) {
        const int e  = abase + q*256 + t;
        const int j  = e & (NN-1);
        const int i  = (e >> 10) & (NN-1);
        const int bb = e >> 20;
        const bool pred = (av16[q] != 0.f) || (j == i);
        const unsigned long long m = __ballot(pred);
        if ((t & 63) == 0) bits[((size_t)bb*NN + i)*16 + (j >> 6)] = m;
    }
}

// ---------------------------------------------------------------------------
// gC (R5): R4 structure + (a) 4-slot prefetch ring (loads issued 3 steps
// ~330cyc ahead, covering L2 latency fully), (b) s_setprio(1) around the
// MFMA trio (T5: the 32-step loop is barrier-free, waves desynchronized ->
// attn-like regime where setprio measured +4-7%).
// smem during loop: [0,4096) edP | [4096,8192) edN | [8192,16896) bits[64][17]
// after loop: comb overlays [0,17408); psum2 at [17408,17920)
// ---------------------------------------------------------------------------
__global__ __launch_bounds__(256, 4) void gC_attn(
    const unsigned short* __restrict__ hpt, const float* __restrict__ asrc,
    const float* __restrict__ edPt, const float* __restrict__ edNt,
    const unsigned long long* __restrict__ bits, float* __restrict__ out)
{
    __shared__ __align__(16) char smem[17920];
    float* edP_lds = (float*)smem;
    float* edN_lds = (float*)(smem + 4096);
    unsigned long long* bits_lds = (unsigned long long*)(smem + 8192);
    float* comb  = (float*)smem;
    float* psum2 = (float*)(smem + 17408);

    const int idx = blockIdx.x;
    const int t   = threadIdx.x;
    const int g   = (idx & 7)*8 + ((idx >> 3) & 7);
    const int it  = idx >> 6;
    const int b   = g >> 4;
    const int i0  = it*64;
    const int wv = t >> 6, lane = t & 63;
    const int l31 = lane & 31, half = lane >> 5;
    const int rg = wv >> 1, jh = wv & 1;
    const int myrow = rg*32 + l31;

    // ---- stage fp32 exp tables + padded bitmask rows (one barrier total) ----
    #pragma unroll
    for (int q = 0; q < 4; ++q) {
        const int j = q*256 + t;
        edP_lds[j] = edPt[(size_t)g*NN + j];
        edN_lds[j] = edNt[(size_t)g*NN + j];
    }
    {
        const unsigned long long* bsrc = bits + ((size_t)b*NN + i0)*16;
        #pragma unroll
        for (int q = 0; q < 4; ++q) {
            const int e = q*256 + t;
            bits_lds[(e >> 4)*17 + (e & 15)] = bsrc[e];
        }
    }
    const float sv    = asrc[(size_t)g*NN + i0 + myrow];
    const float ratio = __expf((LEAK - 1.f)*sv);
    __syncthreads();

    union { short8 v; unsigned short u[8]; } ONES;
    #pragma unroll
    for (int i = 0; i < 8; ++i) ONES.u[i] = 0x3F80;

    float16 acc0, acc1, acc2;
    #pragma unroll
    for (int i = 0; i < 16; ++i) { acc0[i] = 0.f; acc1[i] = 0.f; acc2[i] = 0.f; }

    const unsigned short* hb = hpt + (size_t)g*16*4096;

    short8 B0[4], B1[4];
    #define LOADM(slot, mm) do { \
        const int jt_ = (mm) >> 1; \
        const int ks_ = jh*2 + ((mm) & 1); \
        const size_t base_ = (size_t)jt_*4096; \
        B0[slot] = *(const short8*)&hb[base_ + (((ks_*2 + 0)*2 + half)*32 + l31)*8]; \
        B1[slot] = *(const short8*)&hb[base_ + (((ks_*2 + 1)*2 + half)*32 + l31)*8]; \
    } while (0)

    LOADM(0, 0);
    LOADM(1, 1);
    LOADM(2, 2);

    #pragma unroll
    for (int m = 0; m < 32; ++m) {
        const int jt = m >> 1;
        const int ks = jh*2 + (m & 1);
        const int jo = ks*16 + half*8;

        // issue loads for m+3 (slot free: last consumed at m-1)
        if (m + 3 < 32) LOADM((m + 3) & 3, m + 3);

        const unsigned long long wb = bits_lds[myrow*17 + jt];
        const unsigned bb = (unsigned)(wb >> jo) & 0xffu;

        // broadcast ds_read_b128 x4 (addresses uniform per half-wave)
        const float4 P0 = *(const float4*)&edP_lds[jt*64 + jo];
        const float4 P1 = *(const float4*)&edP_lds[jt*64 + jo + 4];
        const float4 Q0 = *(const float4*)&edN_lds[jt*64 + jo];
        const float4 Q1 = *(const float4*)&edN_lds[jt*64 + jo + 4];
        const float Pp[8] = {P0.x,P0.y,P0.z,P0.w,P1.x,P1.y,P1.z,P1.w};
        const float Nv[8] = {Q0.x,Q0.y,Q0.z,Q0.w,Q1.x,Q1.y,Q1.z,Q1.w};

        float pv[8];
        #pragma unroll
        for (int e2 = 0; e2 < 8; ++e2)
            pv[e2] = mask_by_bit(fmaxf(Pp[e2], ratio*Nv[e2]), bb, e2);

        union { short8 v; unsigned u[4]; } af;
        af.u[0] = pk_bf16(pv[0], pv[1]);
        af.u[1] = pk_bf16(pv[2], pv[3]);
        af.u[2] = pk_bf16(pv[4], pv[5]);
        af.u[3] = pk_bf16(pv[6], pv[7]);

        __builtin_amdgcn_s_setprio(1);
        acc2 = __builtin_amdgcn_mfma_f32_32x32x16_bf16(af.v, ONES.v, acc2, 0, 0, 0);
        acc0 = __builtin_amdgcn_mfma_f32_32x32x16_bf16(af.v, B0[m & 3], acc0, 0, 0, 0);
        acc1 = __builtin_amdgcn_mfma_f32_32x32x16_bf16(af.v, B1[m & 3], acc1, 0, 0, 0);
        __builtin_amdgcn_s_setprio(0);
    }
    #undef LOADM

    __syncthreads();   // tables/bits dead; comb overlays smem from here

    if (l31 == 0) {
        #pragma unroll
        for (int reg = 0; reg < 16; ++reg) {
            const int r = (reg & 3) + 8*(reg >> 2) + 4*half;
            psum2[jh*64 + rg*32 + r] = acc2[reg];
        }
    }
    if (jh == 1) {
        float* cb = comb + (rg*64 + lane)*34;
        #pragma unroll
        for (int i = 0; i < 8; ++i) {
            float2 v0; v0.x = acc0[2*i]; v0.y = acc0[2*i+1];
            float2 v1; v1.x = acc1[2*i]; v1.y = acc1[2*i+1];
            *(float2*)&cb[2*i]      = v0;
            *(float2*)&cb[16 + 2*i] = v1;
        }
    }
    __syncthreads();
    if (jh == 0) {
        const float* cb = comb + (rg*64 + lane)*34;
        #pragma unroll
        for (int i = 0; i < 8; ++i) {
            const float2 v0 = *(const float2*)&cb[2*i];
            const float2 v1 = *(const float2*)&cb[16 + 2*i];
            acc0[2*i] += v0.x; acc0[2*i+1] += v0.y;
            acc1[2*i] += v1.x; acc1[2*i+1] += v1.y;
        }
        #pragma unroll
        for (int reg = 0; reg < 16; ++reg) {
            const int r = (reg & 3) + 8*(reg >> 2) + 4*half;
            const int row = rg*32 + r;
            const float inv = __builtin_amdgcn_rcpf(psum2[row] + psum2[64 + row]);
            const size_t base = ((size_t)g*NN + i0 + row)*NF;
            out[base + l31]      = acc0[reg] * inv;
            out[base + l31 + 32] = acc1[reg] * inv;
        }
    }
}

// ---------------------------------------------------------------------------
extern "C" void kernel_launch(void* const* d_in, const int* in_sizes, int n_in,
                              void* d_out, int out_size, void* d_ws, size_t ws_size,
                              hipStream_t stream)
{
    const float* h     = (const float*)d_in[0];
    const float* adj   = (const float*)d_in[1];
    const float* w     = (const float*)d_in[2];
    const float* a_src = (const float*)d_in[3];
    const float* a_dst = (const float*)d_in[4];
    float* out = (float*)d_out;

    char* ws = (char*)d_ws;
    // ws: hpt bf16 [64][16][4096] frag-order (8,388,608) | asrc (262,144)
    //     | edP (262,144) | edN (262,144) | bits u64 [4][1024][16] (524,288)
    unsigned short* hpt = (unsigned short*)ws;
    float* asrc         = (float*)(ws + 8388608);
    float* edP          = (float*)(ws + 8388608 + 262144);
    float* edN          = (float*)(ws + 8388608 + 524288);
    unsigned long long* bits = (unsigned long long*)(ws + 8388608 + 786432);

    gA_produce<<<dim3(1024), dim3(256), 0, stream>>>(
        h, adj, w, a_src, a_dst, hpt, asrc, edP, edN, bits);
    gC_attn<<<dim3(1024), dim3(256), 0, stream>>>(
        hpt, asrc, edP, edN, bits, out);
}